// Round 1
// baseline (639.284 us; speedup 1.0000x reference)
//
#include <hip/hip_runtime.h>
#include <math.h>

#define D 30

// ---------------- Kernel A: degree accumulation ----------------
__global__ __launch_bounds__(256) void deg_kernel(const int* __restrict__ col,
                                                  const float* __restrict__ ew,
                                                  float* __restrict__ deg, int E) {
    int stride = gridDim.x * blockDim.x;
    for (int e = blockIdx.x * blockDim.x + threadIdx.x; e < E; e += stride) {
        atomicAdd(&deg[col[e]], ew[e]);
    }
}

// ---------------- Kernel B: x = h@W; y = x * rsqrt(deg+1); agg = y ----------------
__global__ __launch_bounds__(256) void gemm_kernel(const float* __restrict__ h,
                                                   const float* __restrict__ W,
                                                   const float* __restrict__ deg,
                                                   float* __restrict__ dis,
                                                   float* __restrict__ y,
                                                   float* __restrict__ agg, int N) {
    __shared__ float hs[256 * D];
    __shared__ float Ws[D * D];
    const int t = threadIdx.x;
    const int nb = blockIdx.x * 256;
    const int cnt = min(256, N - nb);
    const int total = cnt * D;

    for (int i = t; i < D * D; i += 256) Ws[i] = W[i];
    for (int i = t; i < total; i += 256) hs[i] = h[nb * D + i];
    __syncthreads();

    if (t < cnt) {
        const int n = nb + t;
        float x[D];
#pragma unroll
        for (int j = 0; j < D; ++j) x[j] = 0.f;
#pragma unroll
        for (int k = 0; k < D; ++k) {
            const float hv = hs[t * D + k];
#pragma unroll
            for (int j = 0; j < D; ++j) x[j] += hv * Ws[k * D + j];
        }
        const float dv = rsqrtf(deg[n] + 1.0f);  // +1 = self-loop weight
        dis[n] = dv;
#pragma unroll
        for (int j = 0; j < D; ++j) hs[t * D + j] = x[j] * dv;  // own row only, no barrier needed
    }
    __syncthreads();

    for (int i = t; i < total; i += 256) {
        const float v = hs[i];
        y[nb * D + i] = v;
        agg[nb * D + i] = v;  // self-loop contribution initializes the accumulator
    }
}

// ---------------- Kernel C: edge scatter: agg[col] += y[row] * ew ----------------
__global__ __launch_bounds__(256) void scatter_kernel(const int* __restrict__ row,
                                                      const int* __restrict__ colp,
                                                      const float* __restrict__ ew,
                                                      const float* __restrict__ y,
                                                      float* __restrict__ agg, int E) {
    long long tid = (long long)blockIdx.x * blockDim.x + threadIdx.x;
    const long long stride = (long long)gridDim.x * blockDim.x;
    const long long total = (long long)E * 32;
    for (long long i = tid; i < total; i += stride) {
        const int e = (int)(i >> 5);
        const int d = (int)(i & 31);
        if (d < D) {
            const int r = row[e];
            const int c = colp[e];
            const float w = ew[e];
            atomicAdd(&agg[c * D + d], y[r * D + d] * w);
        }
    }
}

// ---------------- Kernel D: out = sigmoid(MLP(relu(dis*agg + convb))) ----------------
__global__ __launch_bounds__(256) void mlp_kernel(const float* __restrict__ agg,
                                                  const float* __restrict__ dis,
                                                  const float* __restrict__ convb,
                                                  const float* __restrict__ w1,
                                                  const float* __restrict__ b1,
                                                  const float* __restrict__ w2,
                                                  const float* __restrict__ b2,
                                                  const float* __restrict__ w3,
                                                  const float* __restrict__ b3,
                                                  const float* __restrict__ w4,
                                                  const float* __restrict__ b4,
                                                  float* __restrict__ out, int N) {
    __shared__ float as[256 * D];
    __shared__ float cb[D];
    __shared__ float W1[300], B1[10], W2[100], B2[10], W3[100], B3[10], W4[10], B4[1];
    const int t = threadIdx.x;
    if (t < D) cb[t] = convb[t];
    for (int i = t; i < 300; i += 256) W1[i] = w1[i];
    if (t < 100) W2[t] = w2[t];
    if (t >= 128 && t < 228) W3[t - 128] = w3[t - 128];
    if (t < 10) { B1[t] = b1[t]; B2[t] = b2[t]; B3[t] = b3[t]; W4[t] = w4[t]; }
    if (t == 0) B4[0] = b4[0];

    const int nb = blockIdx.x * 256;
    const int cnt = min(256, N - nb);
    const int total = cnt * D;
    for (int i = t; i < total; i += 256) as[i] = agg[nb * D + i];
    __syncthreads();

    if (t < cnt) {
        const int n = nb + t;
        const float dv = dis[n];
        float v[D];
#pragma unroll
        for (int j = 0; j < D; ++j) {
            const float z = dv * as[t * D + j] + cb[j];
            v[j] = fmaxf(z, 0.f);
        }
        float h1[10];
#pragma unroll
        for (int j = 0; j < 10; ++j) h1[j] = B1[j];
#pragma unroll
        for (int k = 0; k < D; ++k) {
            const float vv = v[k];
#pragma unroll
            for (int j = 0; j < 10; ++j) h1[j] += vv * W1[k * 10 + j];
        }
#pragma unroll
        for (int j = 0; j < 10; ++j) h1[j] = fmaxf(h1[j], 0.f);

        float h2[10];
#pragma unroll
        for (int j = 0; j < 10; ++j) h2[j] = B2[j];
#pragma unroll
        for (int k = 0; k < 10; ++k) {
            const float vv = h1[k];
#pragma unroll
            for (int j = 0; j < 10; ++j) h2[j] += vv * W2[k * 10 + j];
        }
#pragma unroll
        for (int j = 0; j < 10; ++j) h2[j] = fmaxf(h2[j], 0.f);

        float h3[10];
#pragma unroll
        for (int j = 0; j < 10; ++j) h3[j] = B3[j];
#pragma unroll
        for (int k = 0; k < 10; ++k) {
            const float vv = h2[k];
#pragma unroll
            for (int j = 0; j < 10; ++j) h3[j] += vv * W3[k * 10 + j];
        }
#pragma unroll
        for (int j = 0; j < 10; ++j) h3[j] = fmaxf(h3[j], 0.f);

        float z = B4[0];
#pragma unroll
        for (int k = 0; k < 10; ++k) z += h3[k] * W4[k];
        out[n] = 1.f / (1.f + expf(-z));
    }
}

extern "C" void kernel_launch(void* const* d_in, const int* in_sizes, int n_in,
                              void* d_out, int out_size, void* d_ws, size_t ws_size,
                              hipStream_t stream) {
    const float* h   = (const float*)d_in[0];
    const int*   ei  = (const int*)d_in[1];   // [2, E] row-major: row = ei[0:E], col = ei[E:2E]
    const float* ew  = (const float*)d_in[2];
    const float* convW = (const float*)d_in[3];
    const float* convb = (const float*)d_in[4];
    const float* w1 = (const float*)d_in[5];
    const float* b1 = (const float*)d_in[6];
    const float* w2 = (const float*)d_in[7];
    const float* b2 = (const float*)d_in[8];
    const float* w3 = (const float*)d_in[9];
    const float* b3 = (const float*)d_in[10];
    const float* w4 = (const float*)d_in[11];
    const float* b4 = (const float*)d_in[12];
    float* out = (float*)d_out;

    const int N = in_sizes[0] / D;
    const int E = in_sizes[2];
    const int* row = ei;
    const int* col = ei + E;

    // workspace layout: deg[N] | dis[N] | y[N*D] | agg[N*D]
    float* deg = (float*)d_ws;
    float* dis = deg + N;
    float* y   = dis + N;
    float* agg = y + (size_t)N * D;

    hipMemsetAsync(deg, 0, (size_t)N * sizeof(float), stream);

    const int nblocks = (N + 255) / 256;
    deg_kernel<<<2048, 256, 0, stream>>>(col, ew, deg, E);
    gemm_kernel<<<nblocks, 256, 0, stream>>>(h, convW, deg, dis, y, agg, N);
    scatter_kernel<<<4096, 256, 0, stream>>>(row, col, ew, y, agg, E);
    mlp_kernel<<<nblocks, 256, 0, stream>>>(agg, dis, convb, w1, b1, w2, b2, w3, b3,
                                            w4, b4, out, N);
}